// Round 1
// baseline (704.724 us; speedup 1.0000x reference)
//
#include <hip/hip_runtime.h>
#include <math.h>

#define F_IN 128
#define D_OUT 64
#define LRELU 0.2f
#define BN_EPS 1e-3f

// ---------------- BN statistics: per-column sum / sumsq ----------------
__global__ __launch_bounds__(256) void stats_kernel(const float* __restrict__ x,
                                                    float* __restrict__ sum,
                                                    float* __restrict__ sumsq,
                                                    int N, int rowsPerBlock) {
    int col  = threadIdx.x & 127;
    int half = threadIdx.x >> 7;           // 0/1: two row-streams per block
    int rbeg = blockIdx.x * rowsPerBlock;
    int rend = min(rbeg + rowsPerBlock, N);
    float s = 0.f, sq = 0.f;
    for (int r = rbeg + half; r < rend; r += 2) {
        float v = x[(size_t)r * F_IN + col];
        s += v; sq += v * v;
    }
    __shared__ float ls[256], lsq[256];
    ls[threadIdx.x] = s; lsq[threadIdx.x] = sq;
    __syncthreads();
    if (half == 0) {
        s  += ls[col + 128];
        sq += lsq[col + 128];
        atomicAdd(&sum[col], s);
        atomicAdd(&sumsq[col], sq);
    }
}

__global__ void finalize_stats(float* sum, float* sumsq, int N) {
    int c = threadIdx.x;  // 128 threads
    float mean = sum[c] / (float)N;
    float var  = sumsq[c] / (float)N - mean * mean;
    sum[c]   = mean;
    sumsq[c] = rsqrtf(var + BN_EPS);
}

// ---------------- per-node: xn, mapped = xn@W, a1/a2 quadratic forms ----------------
__global__ __launch_bounds__(256) void node_kernel(const float* __restrict__ x,
                                                   const float* __restrict__ K1,
                                                   const float* __restrict__ K2,
                                                   const float* __restrict__ W,
                                                   const float* __restrict__ meanv,
                                                   const float* __restrict__ rstdv,
                                                   float* __restrict__ a1,
                                                   float* __restrict__ a2,
                                                   float* __restrict__ mapped,
                                                   int N) {
    __shared__ float xnS[32][128];
    __shared__ float mS[128], rS[128];
    int tid = threadIdx.x;
    if (tid < 128) { mS[tid] = meanv[tid]; rS[tid] = rstdv[tid]; }
    __syncthreads();
    int base = blockIdx.x * 32;

    // stage + normalize 32 node rows
    for (int idx = tid; idx < 32 * 128; idx += 256) {
        int n = idx >> 7, c = idx & 127;
        int row = base + n;
        float v = (row < N) ? x[(size_t)row * F_IN + c] : 0.f;
        xnS[n][c] = (v - mS[c]) * rS[c];
    }
    __syncthreads();

    // ---- quadratic forms: a = tanh(xn^T K xn) ----
    // threads: jg = 32 groups of 4 columns, g = 8 groups of 4 nodes
    int jg = tid & 31;
    int g  = tid >> 5;
    float t1[4][4] = {{0}}, t2[4][4] = {{0}};
    for (int k = 0; k < 128; ++k) {
        float4 k1 = *(const float4*)&K1[k * 128 + jg * 4];
        float4 k2 = *(const float4*)&K2[k * 128 + jg * 4];
#pragma unroll
        for (int n = 0; n < 4; ++n) {
            float xv = xnS[g * 4 + n][k];
            t1[n][0] += xv * k1.x; t1[n][1] += xv * k1.y;
            t1[n][2] += xv * k1.z; t1[n][3] += xv * k1.w;
            t2[n][0] += xv * k2.x; t2[n][1] += xv * k2.y;
            t2[n][2] += xv * k2.z; t2[n][3] += xv * k2.w;
        }
    }
#pragma unroll
    for (int n = 0; n < 4; ++n) {
        int ln = g * 4 + n;
        float4 xj = *(const float4*)&xnS[ln][jg * 4];
        float s1 = t1[n][0] * xj.x + t1[n][1] * xj.y + t1[n][2] * xj.z + t1[n][3] * xj.w;
        float s2 = t2[n][0] * xj.x + t2[n][1] * xj.y + t2[n][2] * xj.z + t2[n][3] * xj.w;
#pragma unroll
        for (int off = 16; off > 0; off >>= 1) {   // reduce across the 32 jg lanes
            s1 += __shfl_xor(s1, off, 64);
            s2 += __shfl_xor(s2, off, 64);
        }
        int gnode = base + ln;
        if (jg == 0 && gnode < N) {
            a1[gnode] = tanhf(s1);
            a2[gnode] = tanhf(s2);
        }
    }

    // ---- mapped = xn @ W  (128x64) ----
    // threads: jw = 16 groups of 4 cols, gw = 16 groups of 2 nodes
    int jw = tid & 15;
    int gw = tid >> 4;
    float acc[2][4] = {{0}};
    for (int k = 0; k < 128; ++k) {
        float4 w4 = *(const float4*)&W[k * 64 + jw * 4];
#pragma unroll
        for (int n = 0; n < 2; ++n) {
            float xv = xnS[gw * 2 + n][k];
            acc[n][0] += xv * w4.x; acc[n][1] += xv * w4.y;
            acc[n][2] += xv * w4.z; acc[n][3] += xv * w4.w;
        }
    }
#pragma unroll
    for (int n = 0; n < 2; ++n) {
        int gnode = base + gw * 2 + n;
        if (gnode < N) {
            float4 o = make_float4(acc[n][0], acc[n][1], acc[n][2], acc[n][3]);
            *(float4*)&mapped[(size_t)gnode * 64 + jw * 4] = o;
        }
    }
}

// ---------------- edges: ee = exp(leaky(adj*(a1[s]+a2[d]))), denom, degree ----------------
__global__ __launch_bounds__(256) void edge_kernel(const int* __restrict__ src,
                                                   const int* __restrict__ dst,
                                                   const float* __restrict__ adj,
                                                   const float* __restrict__ a1,
                                                   const float* __restrict__ a2,
                                                   float* __restrict__ ee,
                                                   float* __restrict__ denom,
                                                   int* __restrict__ deg,
                                                   int E) {
    int e = blockIdx.x * 256 + threadIdx.x;
    if (e >= E) return;
    int s = src[e], d = dst[e];
    float v = adj[e] * (a1[s] + a2[d]);
    v = (v > 0.f) ? v : LRELU * v;
    float ex = expf(v);   // softmax max-shift skipped: identical math, bounded e
    ee[e] = ex;
    atomicAdd(&denom[s], ex);
    atomicAdd(&deg[s], 1);
}

// ---------------- exclusive scan of deg -> rowptr (3 small kernels) ----------------
__global__ __launch_bounds__(256) void scan1(const int* __restrict__ deg,
                                             int* __restrict__ pos,
                                             int* __restrict__ bsums, int N) {
    __shared__ int s[256];
    int i = blockIdx.x * 256 + threadIdx.x;
    int v = (i < N) ? deg[i] : 0;
    s[threadIdx.x] = v;
    for (int off = 1; off < 256; off <<= 1) {
        __syncthreads();
        int t = (threadIdx.x >= off) ? s[threadIdx.x - off] : 0;
        __syncthreads();
        s[threadIdx.x] += t;
    }
    __syncthreads();
    if (i < N) pos[i] = s[threadIdx.x];          // block-local inclusive
    if (threadIdx.x == 255) bsums[blockIdx.x] = s[255];
}

__global__ __launch_bounds__(512) void scan2(int* bsums, int nb) {
    __shared__ int s[512];
    int v = (threadIdx.x < nb) ? bsums[threadIdx.x] : 0;
    s[threadIdx.x] = v;
    for (int off = 1; off < 512; off <<= 1) {
        __syncthreads();
        int t = (threadIdx.x >= off) ? s[threadIdx.x - off] : 0;
        __syncthreads();
        s[threadIdx.x] += t;
    }
    __syncthreads();
    if (threadIdx.x < nb) bsums[threadIdx.x] = s[threadIdx.x] - v;  // exclusive
}

__global__ __launch_bounds__(256) void scan3(const int* __restrict__ deg,
                                             int* __restrict__ pos,
                                             const int* __restrict__ bsums,
                                             int* __restrict__ rowptr, int N, int E) {
    int i = blockIdx.x * 256 + threadIdx.x;
    if (i < N) {
        int excl = pos[i] - deg[i] + bsums[blockIdx.x];
        rowptr[i] = excl;
        pos[i] = excl;       // scatter cursor
    }
    if (i == 0) rowptr[N] = E;
}

// ---------------- counting-sort edges by src; fold in 1/denom ----------------
__global__ __launch_bounds__(256) void scatter_kernel(const int* __restrict__ src,
                                                      const int* __restrict__ dst,
                                                      const float* __restrict__ ee,
                                                      const float* __restrict__ denom,
                                                      int* __restrict__ pos,
                                                      int* __restrict__ sortedDst,
                                                      float* __restrict__ sortedVal,
                                                      int E) {
    int e = blockIdx.x * 256 + threadIdx.x;
    if (e >= E) return;
    int s = src[e];
    int p = atomicAdd(&pos[s], 1);
    sortedDst[p] = dst[e];
    sortedVal[p] = ee[e] / denom[s];
}

// ---------------- SpMM: one wave per node, register accumulate, tanh ----------------
__global__ __launch_bounds__(256) void spmm_kernel(const int* __restrict__ rowptr,
                                                   const int* __restrict__ sortedDst,
                                                   const float* __restrict__ sortedVal,
                                                   const float* __restrict__ mapped,
                                                   float* __restrict__ out, int N) {
    int w    = threadIdx.x >> 6;
    int lane = threadIdx.x & 63;
    int node = blockIdx.x * 4 + w;
    if (node >= N) return;
    int beg = rowptr[node], end = rowptr[node + 1];
    float acc = 0.f;
    for (int e = beg; e < end; ++e) {
        int d    = sortedDst[e];
        float wg = sortedVal[e];
        acc += wg * mapped[(size_t)d * 64 + lane];
    }
    out[(size_t)node * 64 + lane] = tanhf(acc);
}

extern "C" void kernel_launch(void* const* d_in, const int* in_sizes, int n_in,
                              void* d_out, int out_size, void* d_ws, size_t ws_size,
                              hipStream_t stream) {
    const float* x   = (const float*)d_in[0];
    const int*   src = (const int*)d_in[1];
    const int*   dst = (const int*)d_in[2];
    const float* adj = (const float*)d_in[3];
    const float* W   = (const float*)d_in[4];
    const float* K1  = (const float*)d_in[5];
    const float* K2  = (const float*)d_in[6];
    float* out = (float*)d_out;

    const int N = in_sizes[0] / F_IN;
    const int E = in_sizes[1];

    // workspace layout
    float* f      = (float*)d_ws;
    float* meanv  = f;                 // 128 (sum -> mean)
    float* rstdv  = f + 128;           // 128 (sumsq -> rstd)
    float* denom  = f + 256;           // N
    int*   deg    = (int*)(denom + N); // N
    float* a1     = (float*)(deg + N); // N
    float* a2     = a1 + N;            // N
    float* mapped = a2 + N;            // N*64
    float* ee     = mapped + (size_t)N * 64;   // E
    int*   rowptr = (int*)(ee + E);    // N+1
    int*   pos    = rowptr + (N + 1);  // N
    int*   bsums  = pos + N;           // <=1024
    int*   sortedDst = bsums + 1024;   // E
    float* sortedVal = (float*)(sortedDst + E); // E

    // zero: sums(256) + denom(N) + deg(N)
    hipMemsetAsync(d_ws, 0, (size_t)(256 + 2 * N) * sizeof(float), stream);

    int rpb = (N + 511) / 512;
    stats_kernel<<<512, 256, 0, stream>>>(x, meanv, rstdv, N, rpb);
    finalize_stats<<<1, 128, 0, stream>>>(meanv, rstdv, N);

    node_kernel<<<(N + 31) / 32, 256, 0, stream>>>(x, K1, K2, W, meanv, rstdv,
                                                   a1, a2, mapped, N);

    edge_kernel<<<(E + 255) / 256, 256, 0, stream>>>(src, dst, adj, a1, a2,
                                                     ee, denom, deg, E);

    int nb1 = (N + 255) / 256;
    scan1<<<nb1, 256, 0, stream>>>(deg, pos, bsums, N);
    scan2<<<1, 512, 0, stream>>>(bsums, nb1);
    scan3<<<nb1, 256, 0, stream>>>(deg, pos, bsums, rowptr, N, E);

    scatter_kernel<<<(E + 255) / 256, 256, 0, stream>>>(src, dst, ee, denom, pos,
                                                        sortedDst, sortedVal, E);

    spmm_kernel<<<(N + 3) / 4, 256, 0, stream>>>(rowptr, sortedDst, sortedVal,
                                                 mapped, out, N);
}

// Round 2
// 631.349 us; speedup vs baseline: 1.1162x; 1.1162x over previous
//
#include <hip/hip_runtime.h>
#include <math.h>

#define F_IN 128
#define D_OUT 64
#define LRELU 0.2f
#define BN_EPS 1e-3f
#define XPITCH 136   // 128 + 8 bf16 pad: row bank-shift 4 -> 2-way max (free)

typedef __attribute__((ext_vector_type(8))) __bf16 bf16x8;
typedef __attribute__((ext_vector_type(4))) __bf16 bf16x4;
typedef __attribute__((ext_vector_type(4))) float f32x4;

// ---------------- BN statistics: per-column sum / sumsq ----------------
__global__ __launch_bounds__(256) void stats_kernel(const float* __restrict__ x,
                                                    float* __restrict__ sum,
                                                    float* __restrict__ sumsq,
                                                    int N, int rowsPerBlock) {
    int col  = threadIdx.x & 127;
    int half = threadIdx.x >> 7;
    int rbeg = blockIdx.x * rowsPerBlock;
    int rend = min(rbeg + rowsPerBlock, N);
    float s = 0.f, sq = 0.f;
    for (int r = rbeg + half; r < rend; r += 2) {
        float v = x[(size_t)r * F_IN + col];
        s += v; sq += v * v;
    }
    __shared__ float ls[256], lsq[256];
    ls[threadIdx.x] = s; lsq[threadIdx.x] = sq;
    __syncthreads();
    if (half == 0) {
        s  += ls[col + 128];
        sq += lsq[col + 128];
        atomicAdd(&sum[col], s);
        atomicAdd(&sumsq[col], sq);
    }
}

__global__ void finalize_stats(float* sum, float* sumsq, int N) {
    int c = threadIdx.x;  // 128 threads
    float mean = sum[c] / (float)N;
    float var  = sumsq[c] / (float)N - mean * mean;
    sum[c]   = mean;
    sumsq[c] = rsqrtf(var + BN_EPS);
}

// ---------------- prep: Bt[c][k] = [K1|K2|W][k][c] split into bf16 hi/lo ----------------
__global__ __launch_bounds__(256) void prep_B(const float* __restrict__ K1,
                                              const float* __restrict__ K2,
                                              const float* __restrict__ W,
                                              __bf16* __restrict__ Bth,
                                              __bf16* __restrict__ Btl) {
    int i = blockIdx.x * 256 + threadIdx.x;   // i = c*128 + k, c in [0,320)
    if (i >= 320 * 128) return;
    int c = i >> 7, k = i & 127;
    float v;
    if (c < 128)      v = K1[k * 128 + c];
    else if (c < 256) v = K2[k * 128 + (c - 128)];
    else              v = W[k * 64 + (c - 256)];
    __bf16 h = (__bf16)v;
    Bth[i] = h;
    Btl[i] = (__bf16)(v - (float)h);
}

// ---------------- per-node MFMA: P = xn @ [K1|K2|W] (split bf16), a1/a2 dots ----------------
__global__ __launch_bounds__(256) void node_kernel(const float* __restrict__ x,
                                                   const __bf16* __restrict__ Bth,
                                                   const __bf16* __restrict__ Btl,
                                                   const float* __restrict__ meanv,
                                                   const float* __restrict__ rstdv,
                                                   float* __restrict__ a1,
                                                   float* __restrict__ a2,
                                                   float* __restrict__ mapped,
                                                   int N) {
    __shared__ __bf16 xh[64][XPITCH];
    __shared__ __bf16 xl[64][XPITCH];
    __shared__ float mS[128], rS[128];
    int tid = threadIdx.x;
    if (tid < 128) { mS[tid] = meanv[tid]; rS[tid] = rstdv[tid]; }
    __syncthreads();
    int base = blockIdx.x * 64;

    // stage + normalize + split 64 rows
#pragma unroll
    for (int it = 0; it < 8; ++it) {
        int chunk = tid + it * 256;          // 0..2047
        int r = chunk >> 5, c4 = (chunk & 31) * 4;
        int row = base + r;
        float f0 = 0.f, f1 = 0.f, f2 = 0.f, f3 = 0.f;
        if (row < N) {
            float4 v  = *(const float4*)&x[(size_t)row * F_IN + c4];
            float4 m  = *(const float4*)&mS[c4];
            float4 rs = *(const float4*)&rS[c4];
            f0 = (v.x - m.x) * rs.x; f1 = (v.y - m.y) * rs.y;
            f2 = (v.z - m.z) * rs.z; f3 = (v.w - m.w) * rs.w;
        }
        __bf16 h0 = (__bf16)f0, h1 = (__bf16)f1, h2 = (__bf16)f2, h3 = (__bf16)f3;
        bf16x4 hv = {h0, h1, h2, h3};
        bf16x4 lv = {(__bf16)(f0 - (float)h0), (__bf16)(f1 - (float)h1),
                     (__bf16)(f2 - (float)h2), (__bf16)(f3 - (float)h3)};
        *(bf16x4*)&xh[r][c4] = hv;
        *(bf16x4*)&xl[r][c4] = lv;
    }
    __syncthreads();

    int lane  = tid & 63;
    int w     = tid >> 6;        // wave = 16-node m-tile
    int col16 = lane & 15;
    int quad  = lane >> 4;
    int kb    = quad * 8;

    // A fragments (hi/lo), loaded once, reused for all 20 col-tiles
    bf16x8 Ah[4], Al[4];
    int arow = w * 16 + col16;
#pragma unroll
    for (int ks = 0; ks < 4; ++ks) {
        Ah[ks] = *(bf16x8*)&xh[arow][ks * 32 + kb];
        Al[ks] = *(bf16x8*)&xl[arow][ks * 32 + kb];
    }

    float pa1[4] = {0, 0, 0, 0}, pa2[4] = {0, 0, 0, 0};

    // paired K1/K2 col-tiles: ct and ct+8 share the same xn column slice
    for (int ct = 0; ct < 8; ++ct) {
        const __bf16* p1h = Bth + (size_t)(ct * 16 + col16) * 128 + kb;
        const __bf16* p1l = Btl + (size_t)(ct * 16 + col16) * 128 + kb;
        f32x4 acc1 = {0, 0, 0, 0}, acc2 = {0, 0, 0, 0};
#pragma unroll
        for (int ks = 0; ks < 4; ++ks) {
            bf16x8 B1h = *(const bf16x8*)(p1h + ks * 32);
            bf16x8 B1l = *(const bf16x8*)(p1l + ks * 32);
            bf16x8 B2h = *(const bf16x8*)(p1h + 128 * 128 + ks * 32);
            bf16x8 B2l = *(const bf16x8*)(p1l + 128 * 128 + ks * 32);
            acc1 = __builtin_amdgcn_mfma_f32_16x16x32_bf16(Ah[ks], B1h, acc1, 0, 0, 0);
            acc1 = __builtin_amdgcn_mfma_f32_16x16x32_bf16(Al[ks], B1h, acc1, 0, 0, 0);
            acc1 = __builtin_amdgcn_mfma_f32_16x16x32_bf16(Ah[ks], B1l, acc1, 0, 0, 0);
            acc2 = __builtin_amdgcn_mfma_f32_16x16x32_bf16(Ah[ks], B2h, acc2, 0, 0, 0);
            acc2 = __builtin_amdgcn_mfma_f32_16x16x32_bf16(Al[ks], B2h, acc2, 0, 0, 0);
            acc2 = __builtin_amdgcn_mfma_f32_16x16x32_bf16(Ah[ks], B2l, acc2, 0, 0, 0);
        }
        int cg = ct * 16 + col16;
#pragma unroll
        for (int reg = 0; reg < 4; ++reg) {
            int lr = w * 16 + quad * 4 + reg;
            float xv = (float)xh[lr][cg] + (float)xl[lr][cg];
            pa1[reg] += acc1[reg] * xv;
            pa2[reg] += acc2[reg] * xv;
        }
    }

    // mapped = xn @ W : col-tiles 16..19 (B cols 256..319)
    for (int ct = 0; ct < 4; ++ct) {
        const __bf16* pwh = Bth + (size_t)(256 + ct * 16 + col16) * 128 + kb;
        const __bf16* pwl = Btl + (size_t)(256 + ct * 16 + col16) * 128 + kb;
        f32x4 acc = {0, 0, 0, 0};
#pragma unroll
        for (int ks = 0; ks < 4; ++ks) {
            bf16x8 Bh = *(const bf16x8*)(pwh + ks * 32);
            bf16x8 Bl = *(const bf16x8*)(pwl + ks * 32);
            acc = __builtin_amdgcn_mfma_f32_16x16x32_bf16(Ah[ks], Bh, acc, 0, 0, 0);
            acc = __builtin_amdgcn_mfma_f32_16x16x32_bf16(Al[ks], Bh, acc, 0, 0, 0);
            acc = __builtin_amdgcn_mfma_f32_16x16x32_bf16(Ah[ks], Bl, acc, 0, 0, 0);
        }
#pragma unroll
        for (int reg = 0; reg < 4; ++reg) {
            int node = base + w * 16 + quad * 4 + reg;
            if (node < N) mapped[(size_t)node * 64 + ct * 16 + col16] = acc[reg];
        }
    }

    // reduce a1/a2 partials across the 16 col lanes of each quad
#pragma unroll
    for (int off = 1; off < 16; off <<= 1) {
#pragma unroll
        for (int reg = 0; reg < 4; ++reg) {
            pa1[reg] += __shfl_xor(pa1[reg], off, 64);
            pa2[reg] += __shfl_xor(pa2[reg], off, 64);
        }
    }
    if (col16 == 0) {
#pragma unroll
        for (int reg = 0; reg < 4; ++reg) {
            int node = base + w * 16 + quad * 4 + reg;
            if (node < N) {
                a1[node] = tanhf(pa1[reg]);
                a2[node] = tanhf(pa2[reg]);
            }
        }
    }
}

// ---------------- edges: ee = exp(leaky(adj*(a1[s]+a2[d]))), pack (dst,ee), degree ----------------
__global__ __launch_bounds__(256) void edge_kernel(const int* __restrict__ src,
                                                   const int* __restrict__ dst,
                                                   const float* __restrict__ adj,
                                                   const float* __restrict__ a1,
                                                   const float* __restrict__ a2,
                                                   int2* __restrict__ packed,
                                                   int* __restrict__ deg,
                                                   int E) {
    int e = blockIdx.x * 256 + threadIdx.x;
    if (e >= E) return;
    int s = src[e], d = dst[e];
    float v = adj[e] * (a1[s] + a2[d]);
    v = (v > 0.f) ? v : LRELU * v;
    float ex = __expf(v);   // max-shift skipped: e bounded in [-0.4, 2]
    packed[e] = make_int2(d, __float_as_int(ex));
    atomicAdd(&deg[s], 1);
}

// ---------------- exclusive scan of deg -> rowptr ----------------
__global__ __launch_bounds__(256) void scan1(const int* __restrict__ deg,
                                             int* __restrict__ pos,
                                             int* __restrict__ bsums, int N) {
    __shared__ int s[256];
    int i = blockIdx.x * 256 + threadIdx.x;
    int v = (i < N) ? deg[i] : 0;
    s[threadIdx.x] = v;
    for (int off = 1; off < 256; off <<= 1) {
        __syncthreads();
        int t = (threadIdx.x >= off) ? s[threadIdx.x - off] : 0;
        __syncthreads();
        s[threadIdx.x] += t;
    }
    __syncthreads();
    if (i < N) pos[i] = s[threadIdx.x];
    if (threadIdx.x == 255) bsums[blockIdx.x] = s[255];
}

__global__ __launch_bounds__(512) void scan2(int* bsums, int nb) {
    __shared__ int s[512];
    int v = (threadIdx.x < nb) ? bsums[threadIdx.x] : 0;
    s[threadIdx.x] = v;
    for (int off = 1; off < 512; off <<= 1) {
        __syncthreads();
        int t = (threadIdx.x >= off) ? s[threadIdx.x - off] : 0;
        __syncthreads();
        s[threadIdx.x] += t;
    }
    __syncthreads();
    if (threadIdx.x < nb) bsums[threadIdx.x] = s[threadIdx.x] - v;
}

__global__ __launch_bounds__(256) void scan3(const int* __restrict__ deg,
                                             int* __restrict__ pos,
                                             const int* __restrict__ bsums,
                                             int* __restrict__ rowptr, int N, int E) {
    int i = blockIdx.x * 256 + threadIdx.x;
    if (i < N) {
        int excl = pos[i] - deg[i] + bsums[blockIdx.x];
        rowptr[i] = excl;
        pos[i] = excl;
    }
    if (i == 0) rowptr[N] = E;
}

// ---------------- counting-sort edges by src (packed 8B payload) ----------------
__global__ __launch_bounds__(256) void scatter_kernel(const int* __restrict__ src,
                                                      const int2* __restrict__ packed,
                                                      int* __restrict__ pos,
                                                      int2* __restrict__ sorted,
                                                      int E) {
    int e = blockIdx.x * 256 + threadIdx.x;
    if (e >= E) return;
    int s = src[e];
    int p = atomicAdd(&pos[s], 1);
    sorted[p] = packed[e];
}

// ---------------- SpMM + inline softmax denom + tanh ----------------
__global__ __launch_bounds__(256) void spmm_kernel(const int* __restrict__ rowptr,
                                                   const int2* __restrict__ sorted,
                                                   const float* __restrict__ mapped,
                                                   float* __restrict__ out, int N) {
    int w    = threadIdx.x >> 6;
    int lane = threadIdx.x & 63;
    int node = blockIdx.x * 4 + w;
    if (node >= N) return;
    int beg = rowptr[node], end = rowptr[node + 1];
    float acc = 0.f, accw = 0.f;
    for (int e = beg; e < end; ++e) {
        int2 pe  = sorted[e];
        float wg = __int_as_float(pe.y);
        accw += wg;
        acc  += wg * mapped[(size_t)pe.x * 64 + lane];
    }
    float inv = (accw != 0.f) ? 1.f / accw : 0.f;
    out[(size_t)node * 64 + lane] = tanhf(acc * inv);
}

extern "C" void kernel_launch(void* const* d_in, const int* in_sizes, int n_in,
                              void* d_out, int out_size, void* d_ws, size_t ws_size,
                              hipStream_t stream) {
    const float* x   = (const float*)d_in[0];
    const int*   src = (const int*)d_in[1];
    const int*   dst = (const int*)d_in[2];
    const float* adj = (const float*)d_in[3];
    const float* W   = (const float*)d_in[4];
    const float* K1  = (const float*)d_in[5];
    const float* K2  = (const float*)d_in[6];
    float* out = (float*)d_out;

    const int N = in_sizes[0] / F_IN;
    const int E = in_sizes[1];

    // workspace layout
    float* meanv  = (float*)d_ws;                 // 128
    float* rstdv  = meanv + 128;                  // 128
    int*   deg    = (int*)(rstdv + 128);          // N  (contiguous with stats for one memset)
    float* a1     = (float*)(deg + N);            // N
    float* a2     = a1 + N;                       // N
    float* mapped = a2 + N;                       // N*64
    int2*  packed = (int2*)(mapped + (size_t)N * 64);   // E (8B aligned: offset even)
    int*   rowptr = (int*)(packed + E);           // N+1
    int*   pos    = rowptr + (N + 1);             // N
    int*   bsums  = pos + N;                      // 1024
    uintptr_t sp  = ((uintptr_t)(bsums + 1024) + 15) & ~(uintptr_t)15;
    int2*  sorted = (int2*)sp;                    // E
    __bf16* Bth   = (__bf16*)(sorted + E);        // 320*128
    __bf16* Btl   = Bth + 320 * 128;              // 320*128

    // zero stats sums + deg (contiguous)
    hipMemsetAsync(d_ws, 0, (size_t)(256 + N) * sizeof(float), stream);

    int rpb = (N + 511) / 512;
    stats_kernel<<<512, 256, 0, stream>>>(x, meanv, rstdv, N, rpb);
    finalize_stats<<<1, 128, 0, stream>>>(meanv, rstdv, N);

    prep_B<<<(320 * 128 + 255) / 256, 256, 0, stream>>>(K1, K2, W, Bth, Btl);

    node_kernel<<<(N + 63) / 64, 256, 0, stream>>>(x, Bth, Btl, meanv, rstdv,
                                                   a1, a2, mapped, N);

    edge_kernel<<<(E + 255) / 256, 256, 0, stream>>>(src, dst, adj, a1, a2,
                                                     packed, deg, E);

    int nb1 = (N + 255) / 256;
    scan1<<<nb1, 256, 0, stream>>>(deg, pos, bsums, N);
    scan2<<<1, 512, 0, stream>>>(bsums, nb1);
    scan3<<<nb1, 256, 0, stream>>>(deg, pos, bsums, rowptr, N, E);

    scatter_kernel<<<(E + 255) / 256, 256, 0, stream>>>(src, packed, pos, sorted, E);

    spmm_kernel<<<(N + 3) / 4, 256, 0, stream>>>(rowptr, sorted, mapped, out, N);
}

// Round 3
// 540.240 us; speedup vs baseline: 1.3045x; 1.1686x over previous
//
#include <hip/hip_runtime.h>
#include <hip/hip_fp16.h>
#include <math.h>

#define F_IN 128
#define D_OUT 64
#define LRELU 0.2f
#define BN_EPS 1e-3f
#define XPITCH 136   // 128 + 8 bf16 pad

typedef __attribute__((ext_vector_type(8))) __bf16 bf16x8;
typedef __attribute__((ext_vector_type(4))) __bf16 bf16x4;
typedef __attribute__((ext_vector_type(4))) float f32x4;

// ---------------- BN statistics: per-column sum / sumsq ----------------
__global__ __launch_bounds__(256) void stats_kernel(const float* __restrict__ x,
                                                    float* __restrict__ sum,
                                                    float* __restrict__ sumsq,
                                                    int N, int rowsPerBlock) {
    int col  = threadIdx.x & 127;
    int half = threadIdx.x >> 7;
    int rbeg = blockIdx.x * rowsPerBlock;
    int rend = min(rbeg + rowsPerBlock, N);
    float s = 0.f, sq = 0.f;
    for (int r = rbeg + half; r < rend; r += 2) {
        float v = x[(size_t)r * F_IN + col];
        s += v; sq += v * v;
    }
    __shared__ float ls[256], lsq[256];
    ls[threadIdx.x] = s; lsq[threadIdx.x] = sq;
    __syncthreads();
    if (half == 0) {
        s  += ls[col + 128];
        sq += lsq[col + 128];
        atomicAdd(&sum[col], s);
        atomicAdd(&sumsq[col], sq);
    }
}

__global__ void finalize_stats(float* sum, float* sumsq, int N) {
    int c = threadIdx.x;  // 128 threads
    float mean = sum[c] / (float)N;
    float var  = sumsq[c] / (float)N - mean * mean;
    sum[c]   = mean;
    sumsq[c] = rsqrtf(var + BN_EPS);
}

// ---------------- prep: Bt[c][k] = [K1|K2|W][k][c] split into bf16 hi/lo ----------------
__global__ __launch_bounds__(256) void prep_B(const float* __restrict__ K1,
                                              const float* __restrict__ K2,
                                              const float* __restrict__ W,
                                              __bf16* __restrict__ Bth,
                                              __bf16* __restrict__ Btl) {
    int i = blockIdx.x * 256 + threadIdx.x;   // i = c*128 + k, c in [0,320)
    if (i >= 320 * 128) return;
    int c = i >> 7, k = i & 127;
    float v;
    if (c < 128)      v = K1[k * 128 + c];
    else if (c < 256) v = K2[k * 128 + (c - 128)];
    else              v = W[k * 64 + (c - 256)];
    __bf16 h = (__bf16)v;
    Bth[i] = h;
    Btl[i] = (__bf16)(v - (float)h);
}

// ---------------- per-node MFMA: P = xn @ [K1|K2|W] (split bf16), a1/a2 dots ----------------
__global__ __launch_bounds__(256) void node_kernel(const float* __restrict__ x,
                                                   const __bf16* __restrict__ Bth,
                                                   const __bf16* __restrict__ Btl,
                                                   const float* __restrict__ meanv,
                                                   const float* __restrict__ rstdv,
                                                   float* __restrict__ a1,
                                                   float* __restrict__ a2,
                                                   __half* __restrict__ mapped,
                                                   int N) {
    __shared__ __bf16 xh[64][XPITCH];
    __shared__ __bf16 xl[64][XPITCH];
    __shared__ float mS[128], rS[128];
    int tid = threadIdx.x;
    if (tid < 128) { mS[tid] = meanv[tid]; rS[tid] = rstdv[tid]; }
    __syncthreads();
    int base = blockIdx.x * 64;

#pragma unroll
    for (int it = 0; it < 8; ++it) {
        int chunk = tid + it * 256;
        int r = chunk >> 5, c4 = (chunk & 31) * 4;
        int row = base + r;
        float f0 = 0.f, f1 = 0.f, f2 = 0.f, f3 = 0.f;
        if (row < N) {
            float4 v  = *(const float4*)&x[(size_t)row * F_IN + c4];
            float4 m  = *(const float4*)&mS[c4];
            float4 rs = *(const float4*)&rS[c4];
            f0 = (v.x - m.x) * rs.x; f1 = (v.y - m.y) * rs.y;
            f2 = (v.z - m.z) * rs.z; f3 = (v.w - m.w) * rs.w;
        }
        __bf16 h0 = (__bf16)f0, h1 = (__bf16)f1, h2 = (__bf16)f2, h3 = (__bf16)f3;
        bf16x4 hv = {h0, h1, h2, h3};
        bf16x4 lv = {(__bf16)(f0 - (float)h0), (__bf16)(f1 - (float)h1),
                     (__bf16)(f2 - (float)h2), (__bf16)(f3 - (float)h3)};
        *(bf16x4*)&xh[r][c4] = hv;
        *(bf16x4*)&xl[r][c4] = lv;
    }
    __syncthreads();

    int lane  = tid & 63;
    int w     = tid >> 6;
    int col16 = lane & 15;
    int quad  = lane >> 4;
    int kb    = quad * 8;

    bf16x8 Ah[4], Al[4];
    int arow = w * 16 + col16;
#pragma unroll
    for (int ks = 0; ks < 4; ++ks) {
        Ah[ks] = *(bf16x8*)&xh[arow][ks * 32 + kb];
        Al[ks] = *(bf16x8*)&xl[arow][ks * 32 + kb];
    }

    float pa1[4] = {0, 0, 0, 0}, pa2[4] = {0, 0, 0, 0};

    for (int ct = 0; ct < 8; ++ct) {
        const __bf16* p1h = Bth + (size_t)(ct * 16 + col16) * 128 + kb;
        const __bf16* p1l = Btl + (size_t)(ct * 16 + col16) * 128 + kb;
        f32x4 acc1 = {0, 0, 0, 0}, acc2 = {0, 0, 0, 0};
#pragma unroll
        for (int ks = 0; ks < 4; ++ks) {
            bf16x8 B1h = *(const bf16x8*)(p1h + ks * 32);
            bf16x8 B1l = *(const bf16x8*)(p1l + ks * 32);
            bf16x8 B2h = *(const bf16x8*)(p1h + 128 * 128 + ks * 32);
            bf16x8 B2l = *(const bf16x8*)(p1l + 128 * 128 + ks * 32);
            acc1 = __builtin_amdgcn_mfma_f32_16x16x32_bf16(Ah[ks], B1h, acc1, 0, 0, 0);
            acc1 = __builtin_amdgcn_mfma_f32_16x16x32_bf16(Al[ks], B1h, acc1, 0, 0, 0);
            acc1 = __builtin_amdgcn_mfma_f32_16x16x32_bf16(Ah[ks], B1l, acc1, 0, 0, 0);
            acc2 = __builtin_amdgcn_mfma_f32_16x16x32_bf16(Ah[ks], B2h, acc2, 0, 0, 0);
            acc2 = __builtin_amdgcn_mfma_f32_16x16x32_bf16(Al[ks], B2h, acc2, 0, 0, 0);
            acc2 = __builtin_amdgcn_mfma_f32_16x16x32_bf16(Ah[ks], B2l, acc2, 0, 0, 0);
        }
        int cg = ct * 16 + col16;
#pragma unroll
        for (int reg = 0; reg < 4; ++reg) {
            int lr = w * 16 + quad * 4 + reg;
            float xv = (float)xh[lr][cg] + (float)xl[lr][cg];
            pa1[reg] += acc1[reg] * xv;
            pa2[reg] += acc2[reg] * xv;
        }
    }

    // mapped = xn @ W (cols 256..319), stored fp16
    for (int ct = 0; ct < 4; ++ct) {
        const __bf16* pwh = Bth + (size_t)(256 + ct * 16 + col16) * 128 + kb;
        const __bf16* pwl = Btl + (size_t)(256 + ct * 16 + col16) * 128 + kb;
        f32x4 acc = {0, 0, 0, 0};
#pragma unroll
        for (int ks = 0; ks < 4; ++ks) {
            bf16x8 Bh = *(const bf16x8*)(pwh + ks * 32);
            bf16x8 Bl = *(const bf16x8*)(pwl + ks * 32);
            acc = __builtin_amdgcn_mfma_f32_16x16x32_bf16(Ah[ks], Bh, acc, 0, 0, 0);
            acc = __builtin_amdgcn_mfma_f32_16x16x32_bf16(Al[ks], Bh, acc, 0, 0, 0);
            acc = __builtin_amdgcn_mfma_f32_16x16x32_bf16(Ah[ks], Bl, acc, 0, 0, 0);
        }
#pragma unroll
        for (int reg = 0; reg < 4; ++reg) {
            int node = base + w * 16 + quad * 4 + reg;
            if (node < N) mapped[(size_t)node * 64 + ct * 16 + col16] = __float2half(acc[reg]);
        }
    }

#pragma unroll
    for (int off = 1; off < 16; off <<= 1) {
#pragma unroll
        for (int reg = 0; reg < 4; ++reg) {
            pa1[reg] += __shfl_xor(pa1[reg], off, 64);
            pa2[reg] += __shfl_xor(pa2[reg], off, 64);
        }
    }
    if (col16 == 0) {
#pragma unroll
        for (int reg = 0; reg < 4; ++reg) {
            int node = base + w * 16 + quad * 4 + reg;
            if (node < N) {
                a1[node] = tanhf(pa1[reg]);
                a2[node] = tanhf(pa2[reg]);
            }
        }
    }
}

// ---------------- degree histogram ----------------
__global__ __launch_bounds__(256) void deg_kernel(const int* __restrict__ src,
                                                  int* __restrict__ deg, int E) {
    int e = blockIdx.x * 256 + threadIdx.x;
    if (e < E) atomicAdd(&deg[src[e]], 1);
}

// ---------------- exclusive scan of deg -> rowptr ----------------
__global__ __launch_bounds__(256) void scan1(const int* __restrict__ deg,
                                             int* __restrict__ pos,
                                             int* __restrict__ bsums, int N) {
    __shared__ int s[256];
    int i = blockIdx.x * 256 + threadIdx.x;
    int v = (i < N) ? deg[i] : 0;
    s[threadIdx.x] = v;
    for (int off = 1; off < 256; off <<= 1) {
        __syncthreads();
        int t = (threadIdx.x >= off) ? s[threadIdx.x - off] : 0;
        __syncthreads();
        s[threadIdx.x] += t;
    }
    __syncthreads();
    if (i < N) pos[i] = s[threadIdx.x];
    if (threadIdx.x == 255) bsums[blockIdx.x] = s[255];
}

__global__ __launch_bounds__(512) void scan2(int* bsums, int nb) {
    __shared__ int s[512];
    int v = (threadIdx.x < nb) ? bsums[threadIdx.x] : 0;
    s[threadIdx.x] = v;
    for (int off = 1; off < 512; off <<= 1) {
        __syncthreads();
        int t = (threadIdx.x >= off) ? s[threadIdx.x - off] : 0;
        __syncthreads();
        s[threadIdx.x] += t;
    }
    __syncthreads();
    if (threadIdx.x < nb) bsums[threadIdx.x] = s[threadIdx.x] - v;
}

__global__ __launch_bounds__(256) void scan3(const int* __restrict__ deg,
                                             int* __restrict__ pos,
                                             const int* __restrict__ bsums,
                                             int* __restrict__ rowptr, int N, int E) {
    int i = blockIdx.x * 256 + threadIdx.x;
    if (i < N) {
        int excl = pos[i] - deg[i] + bsums[blockIdx.x];
        rowptr[i] = excl;
        pos[i] = excl;
    }
    if (i == 0) rowptr[N] = E;
}

// ---------------- fused: edge score + counting-sort scatter ----------------
__global__ __launch_bounds__(256) void scatter_kernel(const int* __restrict__ src,
                                                      const int* __restrict__ dst,
                                                      const float* __restrict__ adj,
                                                      const float* __restrict__ a1,
                                                      const float* __restrict__ a2,
                                                      int* __restrict__ pos,
                                                      int2* __restrict__ sorted,
                                                      int E) {
    int e = blockIdx.x * 256 + threadIdx.x;
    if (e >= E) return;
    int s = src[e], d = dst[e];
    float v = adj[e] * (a1[s] + a2[d]);
    v = (v > 0.f) ? v : LRELU * v;
    float ex = __expf(v);   // max-shift skipped: identical math, e bounded
    int p = atomicAdd(&pos[s], 1);
    sorted[p] = make_int2(d, __float_as_int(ex));
}

// ---------------- SpMM (fp16 gather) + inline softmax denom + tanh ----------------
__global__ __launch_bounds__(256) void spmm_kernel(const int* __restrict__ rowptr,
                                                   const int2* __restrict__ sorted,
                                                   const __half2* __restrict__ mapped,
                                                   float* __restrict__ out, int N) {
    int w    = threadIdx.x >> 6;
    int lane = threadIdx.x & 63;
    int node = blockIdx.x * 4 + w;
    if (node >= N) return;
    int ep = lane >> 5;       // edge parity
    int c2 = lane & 31;       // half2 column pair
    int beg = rowptr[node], end = rowptr[node + 1];
    float ax = 0.f, ay = 0.f, accw = 0.f;
    for (int e = beg + ep; e < end; e += 2) {
        int2 pe  = sorted[e];
        float wg = __int_as_float(pe.y);
        float2 m = __half22float2(mapped[(size_t)pe.x * 32 + c2]);
        accw += wg;
        ax += wg * m.x;
        ay += wg * m.y;
    }
    // combine the two edge-parity halves (lane <-> lane^32)
    ax   += __shfl_xor(ax, 32, 64);
    ay   += __shfl_xor(ay, 32, 64);
    accw += __shfl_xor(accw, 32, 64);
    if (lane < 32) {
        float inv = (accw != 0.f) ? 1.f / accw : 0.f;
        float2 o = make_float2(tanhf(ax * inv), tanhf(ay * inv));
        *(float2*)&out[(size_t)node * 64 + c2 * 2] = o;
    }
}

extern "C" void kernel_launch(void* const* d_in, const int* in_sizes, int n_in,
                              void* d_out, int out_size, void* d_ws, size_t ws_size,
                              hipStream_t stream) {
    const float* x   = (const float*)d_in[0];
    const int*   src = (const int*)d_in[1];
    const int*   dst = (const int*)d_in[2];
    const float* adj = (const float*)d_in[3];
    const float* W   = (const float*)d_in[4];
    const float* K1  = (const float*)d_in[5];
    const float* K2  = (const float*)d_in[6];
    float* out = (float*)d_out;

    const int N = in_sizes[0] / F_IN;
    const int E = in_sizes[1];

    // workspace layout
    float* meanv  = (float*)d_ws;                 // 128
    float* rstdv  = meanv + 128;                  // 128
    int*   deg    = (int*)(rstdv + 128);          // N (contiguous with stats: one memset)
    float* a1     = (float*)(deg + N);            // N
    float* a2     = a1 + N;                       // N
    __half* mapped = (__half*)(a2 + N);           // N*64 fp16
    int*   rowptr = (int*)(mapped + (size_t)N * 64); // N+1
    int*   pos    = rowptr + (N + 1);             // N
    int*   bsums  = pos + N;                      // 1024
    uintptr_t sp  = ((uintptr_t)(bsums + 1024) + 15) & ~(uintptr_t)15;
    int2*  sorted = (int2*)sp;                    // E
    __bf16* Bth   = (__bf16*)(sorted + E);        // 320*128
    __bf16* Btl   = Bth + 320 * 128;              // 320*128

    // zero stats sums + deg
    hipMemsetAsync(d_ws, 0, (size_t)(256 + N) * sizeof(float), stream);

    deg_kernel<<<(E + 255) / 256, 256, 0, stream>>>(src, deg, E);

    int rpb = (N + 511) / 512;
    stats_kernel<<<512, 256, 0, stream>>>(x, meanv, rstdv, N, rpb);
    finalize_stats<<<1, 128, 0, stream>>>(meanv, rstdv, N);

    prep_B<<<(320 * 128 + 255) / 256, 256, 0, stream>>>(K1, K2, W, Bth, Btl);

    node_kernel<<<(N + 63) / 64, 256, 0, stream>>>(x, Bth, Btl, meanv, rstdv,
                                                   a1, a2, mapped, N);

    int nb1 = (N + 255) / 256;
    scan1<<<nb1, 256, 0, stream>>>(deg, pos, bsums, N);
    scan2<<<1, 512, 0, stream>>>(bsums, nb1);
    scan3<<<nb1, 256, 0, stream>>>(deg, pos, bsums, rowptr, N, E);

    scatter_kernel<<<(E + 255) / 256, 256, 0, stream>>>(src, dst, adj, a1, a2,
                                                        pos, sorted, E);

    spmm_kernel<<<(N + 3) / 4, 256, 0, stream>>>(rowptr, sorted,
                                                 (const __half2*)mapped, out, N);
}